// Round 2
// baseline (2076.424 us; speedup 1.0000x reference)
//
#include <hip/hip_runtime.h>

#define TW 32
#define TH 8

// Quantize weights: dst[l][(ic*9+tap)*OC + oc] = clip(rint(src[l][oc][ic*9+tap]/sw[l]), -127, 127)
// stored as int-valued fp32 (exact). src layout is OIHW flattened.
__global__ __launch_bounds__(256) void quantw_kernel(
    const float* __restrict__ src, float* __restrict__ dst,
    const float* __restrict__ sw, int per_layer_sw, int OC, int ICK, int total)
{
    int i = blockIdx.x * 256 + threadIdx.x;
    if (i >= total) return;
    int per = OC * ICK;
    int l = i / per;
    int rem = i - l * per;
    int oc = rem / ICK;
    int k = rem - oc * ICK;
    float s = sw[per_layer_sw ? l : 0];
    float v = src[i] / s;
    v = rintf(v);
    v = fminf(fmaxf(v, -127.0f), 127.0f);
    dst[l * per + k * OC + oc] = v;
}

// Direct 3x3 conv, pad=1, on quantized integer codes.
// in_:  u8 codes [B][CIN][256][256]   (or fp32 x if QIN, quantized during staging)
// out_: u8 codes [B][COUT][256][256]  (or fp32 pixel-shuffled d_out if FINAL)
// resid: optional u8 codes added to input codes before conv (tail residual), saturating at 255.
template<int CIN, int COUT, bool QIN, bool FINAL>
__global__ __launch_bounds__(256) void conv3x3_kernel(
    const void* __restrict__ in_,
    const unsigned char* __restrict__ resid,
    const float* __restrict__ wq,      // [CIN*9][COUT] int-valued fp32
    const float* __restrict__ bias,    // [COUT]
    const float* __restrict__ sw_ptr, int sw_idx,
    const float* __restrict__ s_ptr,
    void* __restrict__ out_)
{
    __shared__ unsigned char tile[CIN][TH + 2][TW + 2];
    const int tid = threadIdx.x;
    const int x0 = blockIdx.x * TW;
    const int y0 = blockIdx.y * TH;
    const int b  = blockIdx.z;
    const float s = s_ptr[0];

    // ---- stage input tile (quantized codes, zero-padded halo) ----
    for (int ch = 0; ch < CIN; ++ch) {
        const int base = ((b * CIN + ch) << 16);
        for (int p = tid; p < (TH + 2) * (TW + 2); p += 256) {
            const int r = p / (TW + 2);
            const int c = p - r * (TW + 2);
            const int gy = y0 + r - 1;
            const int gx = x0 + c - 1;
            unsigned char v = 0;
            if ((unsigned)gy < 256u && (unsigned)gx < 256u) {
                const int gi = base + (gy << 8) + gx;
                if constexpr (QIN) {
                    float xv = ((const float*)in_)[gi];
                    float q = (s == 1.0f) ? xv : (xv / s);
                    q = rintf(q);
                    q = fminf(fmaxf(q, 0.0f), 255.0f);
                    v = (unsigned char)q;
                } else {
                    unsigned int a = ((const unsigned char*)in_)[gi];
                    if (resid) {
                        a += resid[gi];
                        if (a > 255u) a = 255u;
                    }
                    v = (unsigned char)a;
                }
            }
            tile[ch][r][c] = v;
        }
    }
    __syncthreads();

    const int c = tid & (TW - 1);
    const int r = tid >> 5;

    float acc[COUT];
    #pragma unroll
    for (int i = 0; i < COUT; ++i) acc[i] = 0.0f;

    // weights indexed wave-uniformly -> compiler scalarizes to s_load + FMA w/ SGPR
    #pragma unroll 1
    for (int ic = 0; ic < CIN; ++ic) {
        float a[9];
        #pragma unroll
        for (int dy = 0; dy < 3; ++dy)
            #pragma unroll
            for (int dx = 0; dx < 3; ++dx)
                a[dy * 3 + dx] = (float)tile[ic][r + dy][c + dx];
        #pragma unroll
        for (int t = 0; t < 9; ++t) {
            const float* wrow = wq + (ic * 9 + t) * COUT;
            #pragma unroll
            for (int oc = 0; oc < COUT; ++oc)
                acc[oc] = fmaf(a[t], wrow[oc], acc[oc]);
        }
    }

    const float sw = sw_ptr[sw_idx];
    const float alpha = s * sw;
    const int gy = y0 + r;
    const int gx = x0 + c;

    #pragma unroll
    for (int oc = 0; oc < COUT; ++oc) {
        float y = fmaf(alpha, acc[oc], bias[oc]);
        y = fmaxf(y, 0.0f);                          // QuantReLU
        float v = (s == 1.0f) ? y : (y / s);
        v = rintf(v);
        v = fminf(fmaxf(v, 0.0f), 255.0f);           // act fake-quant -> code
        if constexpr (FINAL) {
            float o = (s == 1.0f) ? v : (s * v);
            o = fminf(fmaxf(o, 0.0f), 255.0f);       // final clip
            // pixel shuffle: C=12 -> (c=3, r1, r2), out[b][cc][2y+r1][2x+r2]
            const int cc = oc >> 2;
            const int r1 = (oc >> 1) & 1;
            const int r2 = oc & 1;
            ((float*)out_)[((b * 3 + cc) * 512 + (gy * 2 + r1)) * 512 + (gx * 2 + r2)] = o;
        } else {
            ((unsigned char*)out_)[((b * COUT + oc) << 16) + (gy << 8) + gx] = (unsigned char)v;
        }
    }
}

extern "C" void kernel_launch(void* const* d_in, const int* in_sizes, int n_in,
                              void* d_out, int out_size, void* d_ws, size_t ws_size,
                              hipStream_t stream) {
    const float* x       = (const float*)d_in[0];
    const float* head_w  = (const float*)d_in[1];
    const float* head_b  = (const float*)d_in[2];
    const float* head_sw = (const float*)d_in[3];
    const float* bb_w    = (const float*)d_in[4];
    const float* bb_b    = (const float*)d_in[5];
    const float* bb_sw   = (const float*)d_in[6];
    const float* tr_w    = (const float*)d_in[7];
    const float* tr_b    = (const float*)d_in[8];
    const float* tr_sw   = (const float*)d_in[9];
    const float* act_s   = (const float*)d_in[10];

    char* ws = (char*)d_ws;
    unsigned char* buf0 = (unsigned char*)ws;                 // y0 (head out), kept for residual
    unsigned char* buf1 = buf0 + 16777216;
    unsigned char* buf2 = buf1 + 16777216;
    float* wqH = (float*)(ws + 50331648);                     // [27][32]
    float* wqB = wqH + 864;                                   // [12][288][32]
    float* wqT = wqB + 110592;                                // [288][12]

    quantw_kernel<<<(864 + 255) / 256, 256, 0, stream>>>(head_w, wqH, head_sw, 0, 32, 27, 864);
    quantw_kernel<<<(110592 + 255) / 256, 256, 0, stream>>>(bb_w, wqB, bb_sw, 1, 32, 288, 110592);
    quantw_kernel<<<(3456 + 255) / 256, 256, 0, stream>>>(tr_w, wqT, tr_sw, 0, 12, 288, 3456);

    dim3 grid(256 / TW, 256 / TH, 8);  // (8, 32, 8)

    // head: fp32 x -> quant -> conv -> buf0 (y0)
    conv3x3_kernel<3, 32, true, false><<<grid, 256, 0, stream>>>(
        (const void*)x, nullptr, wqH, head_b, head_sw, 0, act_s, (void*)buf0);

    // backbone: 12 layers ping-pong buf1/buf2 (buf0 preserved for residual)
    const unsigned char* cur = buf0;
    unsigned char* nxt = buf1;
    for (int l = 0; l < 12; ++l) {
        conv3x3_kernel<32, 32, false, false><<<grid, 256, 0, stream>>>(
            (const void*)cur, nullptr, wqB + l * 9216, bb_b + l * 32, bb_sw, l, act_s, (void*)nxt);
        cur = nxt;
        nxt = (nxt == buf1) ? buf2 : buf1;
    }

    // tail: input = sat(cur + buf0), conv 32->12, epilogue = quant + clip + pixel-shuffle -> d_out (fp32)
    conv3x3_kernel<32, 12, false, true><<<grid, 256, 0, stream>>>(
        (const void*)cur, buf0, wqT, tr_b, tr_sw, 0, act_s, d_out);
}

// Round 4
// 390.228 us; speedup vs baseline: 5.3211x; 5.3211x over previous
//
#include <hip/hip_runtime.h>

typedef __bf16 bf16x8 __attribute__((ext_vector_type(8)));
typedef float  f32x16 __attribute__((ext_vector_type(16)));

// ---------------- head weight quant (scalar path, [k=ic*9+tap][oc] fp32) ----------------
__global__ __launch_bounds__(256) void quantw_kernel(
    const float* __restrict__ src, float* __restrict__ dst,
    const float* __restrict__ sw, int per_layer_sw, int OC, int ICK, int total)
{
    int i = blockIdx.x * 256 + threadIdx.x;
    if (i >= total) return;
    int per = OC * ICK;
    int l = i / per;
    int rem = i - l * per;
    int oc = rem / ICK;
    int k = rem - oc * ICK;
    float s = sw[per_layer_sw ? l : 0];
    float v = rintf(src[i] / s);
    v = fminf(fmaxf(v, -127.0f), 127.0f);
    dst[l * per + k * OC + oc] = v;
}

// ---------------- MFMA B prepack: dst[l][s][lane][j] bf16 bits ----------------
// k = s*16 + 8*(lane>>5) + j ; tap = k/32 ; ic = k%32 ; oc = lane&31
__global__ __launch_bounds__(256) void packb_kernel(
    const float* __restrict__ src, unsigned short* __restrict__ dst,
    const float* __restrict__ sw, int per_layer_sw, int OC_real, int total)
{
    int i = blockIdx.x * 256 + threadIdx.x;
    if (i >= total) return;
    int l   = i / 9216;
    int r   = i - l * 9216;
    int s   = r >> 9;
    int lane = (r >> 3) & 63;
    int j   = r & 7;
    int k   = s * 16 + ((lane >> 5) << 3) + j;
    int tap = k >> 5;
    int ic  = k & 31;
    int oc  = lane & 31;
    unsigned short v = 0;
    if (oc < OC_real) {
        float scale = sw[per_layer_sw ? l : 0];
        float w = src[((l * OC_real + oc) * 32 + ic) * 9 + tap];
        float q = rintf(w / scale);
        q = fminf(fmaxf(q, -127.0f), 127.0f);
        union { float f; unsigned int u; } cv; cv.f = q;
        v = (unsigned short)(cv.u >> 16);   // integers |q|<=127 exact in bf16
    }
    dst[i] = v;
}

// ---------------- head: fp32 x (NCHW) -> quant -> 3x3 conv -> u8 codes channel-last ----------------
__global__ __launch_bounds__(256) void head_kernel(
    const float* __restrict__ x, const float* __restrict__ wq,
    const float* __restrict__ bias, const float* __restrict__ sw_ptr,
    const float* __restrict__ s_ptr, unsigned char* __restrict__ out)
{
    __shared__ unsigned char tile[3][10][34];
    const int tid = threadIdx.x;
    const int x0 = blockIdx.x * 32;
    const int y0 = blockIdx.y * 8;
    const int b  = blockIdx.z;
    const float s = s_ptr[0];

    for (int ch = 0; ch < 3; ++ch) {
        const int base = (b * 3 + ch) << 16;
        for (int p = tid; p < 10 * 34; p += 256) {
            int r = p / 34, c = p - r * 34;
            int gy = y0 + r - 1, gx = x0 + c - 1;
            unsigned char v = 0;
            if ((unsigned)gy < 256u && (unsigned)gx < 256u) {
                float xv = x[base + (gy << 8) + gx];
                float q = (s == 1.0f) ? xv : (xv / s);
                q = rintf(q);
                q = fminf(fmaxf(q, 0.0f), 255.0f);
                v = (unsigned char)q;
            }
            tile[ch][r][c] = v;
        }
    }
    __syncthreads();

    const int c = tid & 31, r = tid >> 5;
    float acc[32];
    #pragma unroll
    for (int i = 0; i < 32; ++i) acc[i] = 0.0f;

    #pragma unroll
    for (int ic = 0; ic < 3; ++ic) {
        float a[9];
        #pragma unroll
        for (int dy = 0; dy < 3; ++dy)
            #pragma unroll
            for (int dx = 0; dx < 3; ++dx)
                a[dy * 3 + dx] = (float)tile[ic][r + dy][c + dx];
        #pragma unroll
        for (int t = 0; t < 9; ++t) {
            const float* wrow = wq + (ic * 9 + t) * 32;
            #pragma unroll
            for (int oc = 0; oc < 32; ++oc)
                acc[oc] = fmaf(a[t], wrow[oc], acc[oc]);
        }
    }

    const float alpha = s * sw_ptr[0];
    unsigned int w8[8] = {0,0,0,0,0,0,0,0};
    #pragma unroll
    for (int oc = 0; oc < 32; ++oc) {
        float y = fmaf(alpha, acc[oc], bias[oc]);
        y = fmaxf(y, 0.0f);
        float v = (s == 1.0f) ? y : (y / s);
        v = rintf(v);
        v = fminf(fmaxf(v, 0.0f), 255.0f);
        w8[oc >> 2] |= ((unsigned int)(unsigned char)v) << (8 * (oc & 3));
    }
    uint4* dst = (uint4*)(out + (size_t)((((b << 8) + (y0 + r)) << 8) + (x0 + c)) * 32);
    dst[0] = make_uint4(w8[0], w8[1], w8[2], w8[3]);
    dst[1] = make_uint4(w8[4], w8[5], w8[6], w8[7]);
}

// ---------------- backbone/tail: implicit-GEMM 3x3 conv via mfma_f32_32x32x16_bf16 ----------------
// in:  u8 codes [B][256][256][32] channel-last
// out: u8 codes same layout (!FINAL) or fp32 pixel-shuffled d_out (FINAL, oc<12)
template<bool FINAL>
__global__ __launch_bounds__(256, 2) void qconv_mfma_kernel(
    const unsigned char* __restrict__ in,
    const unsigned char* __restrict__ resid,
    const unsigned short* __restrict__ Bp,   // [18][64][8] bf16 bits, fragment-ready
    const float* __restrict__ bias,
    const float* __restrict__ sw_ptr, int sw_idx,
    const float* __restrict__ s_ptr,
    void* __restrict__ out)
{
    __shared__ uint4 aT[2448];   // [yt:18][xt:34][cb:4] 16B chunks, cb XOR-swizzled by xt
    __shared__ uint4 bT[1152];   // [s:18][lane:64]
    const int tid = threadIdx.x;
    const int x0 = blockIdx.x << 5;   // tile 32 wide
    const int y0 = blockIdx.y << 4;   // tile 16 high
    const int b  = blockIdx.z;

    // stage B (18 KB, linear)
    #pragma unroll
    for (int it = 0; it < 5; ++it) {
        int bi = tid + it * 256;
        if (bi < 1152) bT[bi] = ((const uint4*)Bp)[bi];
    }
    // stage A tile: u8 -> bf16, swizzled chunks
    #pragma unroll
    for (int it = 0; it < 5; ++it) {
        int ci = tid + it * 256;
        if (ci < 1224) {                       // 18*34*2 half-pixel chunks
            int yt  = ci / 68;
            int rem = ci - yt * 68;
            int xt  = rem >> 1;
            int ch  = rem & 1;                 // which 16-channel half
            int gy = y0 + yt - 1;
            int gx = x0 + xt - 1;
            uint4 raw = make_uint4(0, 0, 0, 0);
            uint4 res = make_uint4(0, 0, 0, 0);
            if ((unsigned)gy < 256u && (unsigned)gx < 256u) {
                size_t off = (size_t)((((b << 8) + gy) << 8) + gx) * 32 + (ch << 4);
                raw = *(const uint4*)(in + off);
                if (FINAL) res = *(const uint4*)(resid + off);
            }
            unsigned int ow[8];
            const unsigned int* rw = (const unsigned int*)&raw;
            const unsigned int* rr = (const unsigned int*)&res;
            #pragma unroll
            for (int w = 0; w < 4; ++w) {
                unsigned int v = rw[w], rv = rr[w];
                #pragma unroll
                for (int hb = 0; hb < 2; ++hb) {
                    unsigned int a0 = (v >> (16 * hb)) & 0xffu;
                    unsigned int a1 = (v >> (16 * hb + 8)) & 0xffu;
                    if (FINAL) {
                        a0 += (rv >> (16 * hb)) & 0xffu;      if (a0 > 255u) a0 = 255u;
                        a1 += (rv >> (16 * hb + 8)) & 0xffu;  if (a1 > 255u) a1 = 255u;
                    }
                    union { float f; unsigned int u; } c0, c1;
                    c0.f = (float)a0; c1.f = (float)a1;       // integers <=255: exact in bf16
                    ow[2 * w + hb] = (c0.u >> 16) | (c1.u & 0xffff0000u);
                }
            }
            int swz  = (xt & 3) ^ ((xt >> 2) & 3);
            int base = (yt * 34 + xt) << 2;
            aT[base + (((ch << 1) + 0) ^ swz)] = make_uint4(ow[0], ow[1], ow[2], ow[3]);
            aT[base + (((ch << 1) + 1) ^ swz)] = make_uint4(ow[4], ow[5], ow[6], ow[7]);
        }
    }
    __syncthreads();

    const int lane = tid & 63;
    const int wid  = tid >> 6;
    const int px   = lane & 31;
    const int half = lane >> 5;
    const int py0  = wid << 2;      // 4 pixel-rows per wave

    f32x16 acc[4];
    #pragma unroll
    for (int p = 0; p < 4; ++p)
        #pragma unroll
        for (int i = 0; i < 16; ++i) acc[p][i] = 0.0f;

    #pragma unroll
    for (int ich = 0; ich < 2; ++ich) {
        // A-frags: rows py0..py0+5, dx 0..2, this ic-half — reused across all dy
        bf16x8 af[6][3];
        #pragma unroll
        for (int yl = 0; yl < 6; ++yl) {
            #pragma unroll
            for (int dx = 0; dx < 3; ++dx) {
                int xt = px + dx;
                int cb = (ich << 1) + half;
                int chunk = ((py0 + yl) * 34 + xt) * 4 + (cb ^ ((xt & 3) ^ ((xt >> 2) & 3)));
                af[yl][dx] = *(const bf16x8*)&aT[chunk];
            }
        }
        #pragma unroll
        for (int t = 0; t < 9; ++t) {
            const int dy = t / 3, dx = t - dy * 3;
            bf16x8 bfr = *(const bf16x8*)&bT[((t << 1) + ich) * 64 + lane];
            acc[0] = __builtin_amdgcn_mfma_f32_32x32x16_bf16(af[dy + 0][dx], bfr, acc[0], 0, 0, 0);
            acc[1] = __builtin_amdgcn_mfma_f32_32x32x16_bf16(af[dy + 1][dx], bfr, acc[1], 0, 0, 0);
            acc[2] = __builtin_amdgcn_mfma_f32_32x32x16_bf16(af[dy + 2][dx], bfr, acc[2], 0, 0, 0);
            acc[3] = __builtin_amdgcn_mfma_f32_32x32x16_bf16(af[dy + 3][dx], bfr, acc[3], 0, 0, 0);
        }
    }

    // epilogue: D col = lane&31 = oc ; row i = (r&3) + 8*(r>>2) + 4*(lane>>5)
    const float s = s_ptr[0];
    const float alpha = s * sw_ptr[sw_idx];
    const int oc = lane & 31;
    const int OCr = FINAL ? 12 : 32;
    const float bv = (oc < OCr) ? bias[oc] : 0.0f;

    #pragma unroll
    for (int py = 0; py < 4; ++py) {
        const int gy = y0 + py0 + py;
        #pragma unroll
        for (int r = 0; r < 16; ++r) {
            float y = fmaf(alpha, acc[py][r], bv);
            y = fmaxf(y, 0.0f);
            float v = (s == 1.0f) ? y : (y / s);
            v = rintf(v);
            v = fminf(fmaxf(v, 0.0f), 255.0f);
            const int i  = (r & 3) + ((r >> 2) << 3) + (half << 2);
            const int gx = x0 + i;
            if (!FINAL) {
                ((unsigned char*)out)[((size_t)((((b << 8) + gy) << 8) + gx) << 5) + oc] = (unsigned char)v;
            } else if (oc < 12) {
                float o = (s == 1.0f) ? v : fminf(fmaxf(s * v, 0.0f), 255.0f);
                const int cc = oc >> 2, r1 = (oc >> 1) & 1, r2 = oc & 1;
                ((float*)out)[(size_t)(((b * 3 + cc) << 9) + (gy << 1) + r1) * 512 + (gx << 1) + r2] = o;
            }
        }
    }
}

extern "C" void kernel_launch(void* const* d_in, const int* in_sizes, int n_in,
                              void* d_out, int out_size, void* d_ws, size_t ws_size,
                              hipStream_t stream) {
    const float* x       = (const float*)d_in[0];
    const float* head_w  = (const float*)d_in[1];
    const float* head_b  = (const float*)d_in[2];
    const float* head_sw = (const float*)d_in[3];
    const float* bb_w    = (const float*)d_in[4];
    const float* bb_b    = (const float*)d_in[5];
    const float* bb_sw   = (const float*)d_in[6];
    const float* tr_w    = (const float*)d_in[7];
    const float* tr_b    = (const float*)d_in[8];
    const float* tr_sw   = (const float*)d_in[9];
    const float* act_s   = (const float*)d_in[10];

    char* ws = (char*)d_ws;
    unsigned char* buf0 = (unsigned char*)ws;            // y0, channel-last u8 [8][256][256][32]
    unsigned char* buf1 = buf0 + 16777216;
    unsigned char* buf2 = buf1 + 16777216;
    float* wqH = (float*)(ws + 50331648);                         // [27][32] fp32
    unsigned short* BpB = (unsigned short*)(ws + 50331648 + 4096); // 12 x [18][64][8] bf16
    unsigned short* BpT = BpB + 110592;                            // [18][64][8] bf16

    quantw_kernel<<<(864 + 255) / 256, 256, 0, stream>>>(head_w, wqH, head_sw, 0, 32, 27, 864);
    packb_kernel<<<(110592 + 255) / 256, 256, 0, stream>>>(bb_w, BpB, bb_sw, 1, 32, 110592);
    packb_kernel<<<(9216 + 255) / 256, 256, 0, stream>>>(tr_w, BpT, tr_sw, 0, 12, 9216);

    // head
    head_kernel<<<dim3(8, 32, 8), 256, 0, stream>>>(x, wqH, head_b, head_sw, act_s, buf0);

    // backbone: 12 MFMA layers, ping-pong buf1/buf2 (buf0 preserved for residual)
    dim3 gridB(8, 16, 8);
    const unsigned char* cur = buf0;
    unsigned char* nxt = buf1;
    for (int l = 0; l < 12; ++l) {
        qconv_mfma_kernel<false><<<gridB, 256, 0, stream>>>(
            cur, nullptr, BpB + l * 9216, bb_b + l * 32, bb_sw, l, act_s, (void*)nxt);
        cur = nxt;
        nxt = (nxt == buf1) ? buf2 : buf1;
    }

    // tail: input = sat(cur + buf0), conv 32->12(pad 32), pixel-shuffle fp32 out
    qconv_mfma_kernel<true><<<gridB, 256, 0, stream>>>(
        cur, buf0, BpT, tr_b, tr_sw, 0, act_s, d_out);
}

// Round 5
// 378.593 us; speedup vs baseline: 5.4846x; 1.0307x over previous
//
#include <hip/hip_runtime.h>

typedef __bf16 bf16x8 __attribute__((ext_vector_type(8)));
typedef float  f32x16 __attribute__((ext_vector_type(16)));

// ---------------- head weight quant (scalar path, [k=ic*9+tap][oc] fp32) ----------------
__global__ __launch_bounds__(256) void quantw_kernel(
    const float* __restrict__ src, float* __restrict__ dst,
    const float* __restrict__ sw, int per_layer_sw, int OC, int ICK, int total)
{
    int i = blockIdx.x * 256 + threadIdx.x;
    if (i >= total) return;
    int per = OC * ICK;
    int l = i / per;
    int rem = i - l * per;
    int oc = rem / ICK;
    int k = rem - oc * ICK;
    float s = sw[per_layer_sw ? l : 0];
    float v = rintf(src[i] / s);
    v = fminf(fmaxf(v, -127.0f), 127.0f);
    dst[l * per + k * OC + oc] = v;
}

// ---------------- MFMA W prepack: dst[l][s][lane][j] bf16 bits ----------------
// k = s*16 + 8*(lane>>5) + j ; tap = k/32 ; ic = k%32 ; oc = lane&31
// (used as the A operand now: row = lane&31 = oc, same k mapping)
__global__ __launch_bounds__(256) void packb_kernel(
    const float* __restrict__ src, unsigned short* __restrict__ dst,
    const float* __restrict__ sw, int per_layer_sw, int OC_real, int total)
{
    int i = blockIdx.x * 256 + threadIdx.x;
    if (i >= total) return;
    int l   = i / 9216;
    int r   = i - l * 9216;
    int s   = r >> 9;
    int lane = (r >> 3) & 63;
    int j   = r & 7;
    int k   = s * 16 + ((lane >> 5) << 3) + j;
    int tap = k >> 5;
    int ic  = k & 31;
    int oc  = lane & 31;
    unsigned short v = 0;
    if (oc < OC_real) {
        float scale = sw[per_layer_sw ? l : 0];
        float w = src[((l * OC_real + oc) * 32 + ic) * 9 + tap];
        float q = rintf(w / scale);
        q = fminf(fmaxf(q, -127.0f), 127.0f);
        union { float f; unsigned int u; } cv; cv.f = q;
        v = (unsigned short)(cv.u >> 16);   // integers |q|<=127 exact in bf16
    }
    dst[i] = v;
}

// ---------------- head: fp32 x (NCHW) -> quant -> 3x3 conv -> u8 codes channel-last ----------------
__global__ __launch_bounds__(256) void head_kernel(
    const float* __restrict__ x, const float* __restrict__ wq,
    const float* __restrict__ bias, const float* __restrict__ sw_ptr,
    const float* __restrict__ s_ptr, unsigned char* __restrict__ out)
{
    __shared__ unsigned char tile[3][10][34];
    const int tid = threadIdx.x;
    const int x0 = blockIdx.x * 32;
    const int y0 = blockIdx.y * 8;
    const int b  = blockIdx.z;
    const float s = s_ptr[0];

    for (int ch = 0; ch < 3; ++ch) {
        const int base = (b * 3 + ch) << 16;
        for (int p = tid; p < 10 * 34; p += 256) {
            int r = p / 34, c = p - r * 34;
            int gy = y0 + r - 1, gx = x0 + c - 1;
            unsigned char v = 0;
            if ((unsigned)gy < 256u && (unsigned)gx < 256u) {
                float xv = x[base + (gy << 8) + gx];
                float q = (s == 1.0f) ? xv : (xv / s);
                q = rintf(q);
                q = fminf(fmaxf(q, 0.0f), 255.0f);
                v = (unsigned char)q;
            }
            tile[ch][r][c] = v;
        }
    }
    __syncthreads();

    const int c = tid & 31, r = tid >> 5;
    float acc[32];
    #pragma unroll
    for (int i = 0; i < 32; ++i) acc[i] = 0.0f;

    #pragma unroll
    for (int ic = 0; ic < 3; ++ic) {
        float a[9];
        #pragma unroll
        for (int dy = 0; dy < 3; ++dy)
            #pragma unroll
            for (int dx = 0; dx < 3; ++dx)
                a[dy * 3 + dx] = (float)tile[ic][r + dy][c + dx];
        #pragma unroll
        for (int t = 0; t < 9; ++t) {
            const float* wrow = wq + (ic * 9 + t) * 32;
            #pragma unroll
            for (int oc = 0; oc < 32; ++oc)
                acc[oc] = fmaf(a[t], wrow[oc], acc[oc]);
        }
    }

    const float alpha = s * sw_ptr[0];
    unsigned int w8[8] = {0,0,0,0,0,0,0,0};
    #pragma unroll
    for (int oc = 0; oc < 32; ++oc) {
        float y = fmaf(alpha, acc[oc], bias[oc]);
        y = fmaxf(y, 0.0f);
        float v = (s == 1.0f) ? y : (y / s);
        v = rintf(v);
        v = fminf(fmaxf(v, 0.0f), 255.0f);
        w8[oc >> 2] |= ((unsigned int)(unsigned char)v) << (8 * (oc & 3));
    }
    uint4* dst = (uint4*)(out + (size_t)((((b << 8) + (y0 + r)) << 8) + (x0 + c)) * 32);
    dst[0] = make_uint4(w8[0], w8[1], w8[2], w8[3]);
    dst[1] = make_uint4(w8[4], w8[5], w8[6], w8[7]);
}

// ---------------- backbone/tail: implicit-GEMM 3x3 conv via mfma_f32_32x32x16_bf16 ----------------
// D = W * Act^T : A-operand = weight frag (row=oc), B-operand = activation frag (col=pixel).
// Epilogue: lane = pixel-x, r -> oc = (r&3)+8*(r>>2)+4*half  => 4 consecutive r = 4 consecutive
// oc bytes = one packed u32 store.
template<bool FINAL>
__global__ __launch_bounds__(256, 2) void qconv_mfma_kernel(
    const unsigned char* __restrict__ in,
    const unsigned char* __restrict__ resid,
    const unsigned short* __restrict__ Bp,   // [18][64][8] bf16 bits, fragment-ready
    const float* __restrict__ bias,
    const float* __restrict__ sw_ptr, int sw_idx,
    const float* __restrict__ s_ptr,
    void* __restrict__ out)
{
    __shared__ uint4 aT[2448];   // [yt:18][xt:34][cb:4] 16B chunks, cb XOR-swizzled by xt
    __shared__ uint4 bT[1152];   // [s:18][lane:64]
    const int tid = threadIdx.x;
    const int x0 = blockIdx.x << 5;   // tile 32 wide
    const int y0 = blockIdx.y << 4;   // tile 16 high
    const int b  = blockIdx.z;

    // stage W (18 KB, linear)
    #pragma unroll
    for (int it = 0; it < 5; ++it) {
        int bi = tid + it * 256;
        if (bi < 1152) bT[bi] = ((const uint4*)Bp)[bi];
    }
    // stage A tile: u8 -> bf16, swizzled chunks
    #pragma unroll
    for (int it = 0; it < 5; ++it) {
        int ci = tid + it * 256;
        if (ci < 1224) {                       // 18*34*2 half-pixel chunks
            int yt  = ci / 68;
            int rem = ci - yt * 68;
            int xt  = rem >> 1;
            int ch  = rem & 1;                 // which 16-channel half
            int gy = y0 + yt - 1;
            int gx = x0 + xt - 1;
            uint4 raw = make_uint4(0, 0, 0, 0);
            uint4 res = make_uint4(0, 0, 0, 0);
            if ((unsigned)gy < 256u && (unsigned)gx < 256u) {
                size_t off = (size_t)((((b << 8) + gy) << 8) + gx) * 32 + (ch << 4);
                raw = *(const uint4*)(in + off);
                if (FINAL) res = *(const uint4*)(resid + off);
            }
            unsigned int ow[8];
            const unsigned int* rw = (const unsigned int*)&raw;
            const unsigned int* rr = (const unsigned int*)&res;
            #pragma unroll
            for (int w = 0; w < 4; ++w) {
                unsigned int v = rw[w], rv = rr[w];
                #pragma unroll
                for (int hb = 0; hb < 2; ++hb) {
                    unsigned int a0 = (v >> (16 * hb)) & 0xffu;
                    unsigned int a1 = (v >> (16 * hb + 8)) & 0xffu;
                    if (FINAL) {
                        a0 += (rv >> (16 * hb)) & 0xffu;      if (a0 > 255u) a0 = 255u;
                        a1 += (rv >> (16 * hb + 8)) & 0xffu;  if (a1 > 255u) a1 = 255u;
                    }
                    union { float f; unsigned int u; } c0, c1;
                    c0.f = (float)a0; c1.f = (float)a1;       // integers <=255: exact in bf16
                    ow[2 * w + hb] = (c0.u >> 16) | (c1.u & 0xffff0000u);
                }
            }
            int swz  = (xt & 3) ^ ((xt >> 2) & 3);
            int base = (yt * 34 + xt) << 2;
            aT[base + (((ch << 1) + 0) ^ swz)] = make_uint4(ow[0], ow[1], ow[2], ow[3]);
            aT[base + (((ch << 1) + 1) ^ swz)] = make_uint4(ow[4], ow[5], ow[6], ow[7]);
        }
    }
    __syncthreads();

    const int lane = tid & 63;
    const int wid  = tid >> 6;
    const int px   = lane & 31;
    const int half = lane >> 5;
    const int py0  = wid << 2;      // 4 pixel-rows per wave

    f32x16 acc[4];
    #pragma unroll
    for (int p = 0; p < 4; ++p)
        #pragma unroll
        for (int i = 0; i < 16; ++i) acc[p][i] = 0.0f;

    #pragma unroll
    for (int ich = 0; ich < 2; ++ich) {
        // act frags (B operand): rows py0..py0+5, dx 0..2, this ic-half — reused across all dy
        bf16x8 af[6][3];
        #pragma unroll
        for (int yl = 0; yl < 6; ++yl) {
            #pragma unroll
            for (int dx = 0; dx < 3; ++dx) {
                int xt = px + dx;
                int cb = (ich << 1) + half;
                int chunk = ((py0 + yl) * 34 + xt) * 4 + (cb ^ ((xt & 3) ^ ((xt >> 2) & 3)));
                af[yl][dx] = *(const bf16x8*)&aT[chunk];
            }
        }
        #pragma unroll
        for (int t = 0; t < 9; ++t) {
            const int dy = t / 3, dx = t - dy * 3;
            bf16x8 wfr = *(const bf16x8*)&bT[((t << 1) + ich) * 64 + lane];
            // D = W * Act^T  (operand swap: weights are A, activations are B)
            acc[0] = __builtin_amdgcn_mfma_f32_32x32x16_bf16(wfr, af[dy + 0][dx], acc[0], 0, 0, 0);
            acc[1] = __builtin_amdgcn_mfma_f32_32x32x16_bf16(wfr, af[dy + 1][dx], acc[1], 0, 0, 0);
            acc[2] = __builtin_amdgcn_mfma_f32_32x32x16_bf16(wfr, af[dy + 2][dx], acc[2], 0, 0, 0);
            acc[3] = __builtin_amdgcn_mfma_f32_32x32x16_bf16(wfr, af[dy + 3][dx], acc[3], 0, 0, 0);
        }
    }

    // epilogue: D col = lane&31 = pixel-x ; row r -> oc = (r&3) + 8*(r>>2) + 4*half
    const float s = s_ptr[0];
    const float alpha = s * sw_ptr[sw_idx];
    const int gx = x0 + px;

    if (!FINAL) {
        // per lane: 16 oc values in 4 contiguous-byte groups -> 4 u32 stores per py
        float bv[16];
        #pragma unroll
        for (int r = 0; r < 16; ++r)
            bv[r] = bias[(r & 3) + ((r >> 2) << 3) + (half << 2)];
        #pragma unroll
        for (int py = 0; py < 4; ++py) {
            const int gy = y0 + py0 + py;
            unsigned char* pout = (unsigned char*)out + (((size_t)((((b << 8) + gy) << 8) + gx)) << 5);
            #pragma unroll
            for (int q = 0; q < 4; ++q) {
                unsigned int wv = 0;
                #pragma unroll
                for (int j = 0; j < 4; ++j) {
                    float y = fmaf(alpha, acc[py][4 * q + j], bv[4 * q + j]);
                    y = fmaxf(y, 0.0f);
                    float v = (s == 1.0f) ? y : (y / s);
                    v = rintf(v);
                    v = fminf(fmaxf(v, 0.0f), 255.0f);
                    wv |= ((unsigned int)v) << (8 * j);
                }
                *(unsigned int*)(pout + 8 * q + 4 * half) = wv;
            }
        }
    } else {
        #pragma unroll
        for (int py = 0; py < 4; ++py) {
            const int gy = y0 + py0 + py;
            #pragma unroll
            for (int r = 0; r < 16; ++r) {
                const int oc = (r & 3) + ((r >> 2) << 3) + (half << 2);
                if (oc < 12) {
                    float y = fmaf(alpha, acc[py][r], bias[oc]);
                    y = fmaxf(y, 0.0f);
                    float v = (s == 1.0f) ? y : (y / s);
                    v = rintf(v);
                    v = fminf(fmaxf(v, 0.0f), 255.0f);
                    float o = (s == 1.0f) ? v : fminf(fmaxf(s * v, 0.0f), 255.0f);
                    const int cc = oc >> 2, r1 = (oc >> 1) & 1, r2 = oc & 1;
                    ((float*)out)[(size_t)(((b * 3 + cc) << 9) + (gy << 1) + r1) * 512 + (gx << 1) + r2] = o;
                }
            }
        }
    }
}

extern "C" void kernel_launch(void* const* d_in, const int* in_sizes, int n_in,
                              void* d_out, int out_size, void* d_ws, size_t ws_size,
                              hipStream_t stream) {
    const float* x       = (const float*)d_in[0];
    const float* head_w  = (const float*)d_in[1];
    const float* head_b  = (const float*)d_in[2];
    const float* head_sw = (const float*)d_in[3];
    const float* bb_w    = (const float*)d_in[4];
    const float* bb_b    = (const float*)d_in[5];
    const float* bb_sw   = (const float*)d_in[6];
    const float* tr_w    = (const float*)d_in[7];
    const float* tr_b    = (const float*)d_in[8];
    const float* tr_sw   = (const float*)d_in[9];
    const float* act_s   = (const float*)d_in[10];

    char* ws = (char*)d_ws;
    unsigned char* buf0 = (unsigned char*)ws;            // y0, channel-last u8 [8][256][256][32]
    unsigned char* buf1 = buf0 + 16777216;
    unsigned char* buf2 = buf1 + 16777216;
    float* wqH = (float*)(ws + 50331648);                         // [27][32] fp32
    unsigned short* BpB = (unsigned short*)(ws + 50331648 + 4096); // 12 x [18][64][8] bf16
    unsigned short* BpT = BpB + 110592;                            // [18][64][8] bf16

    quantw_kernel<<<(864 + 255) / 256, 256, 0, stream>>>(head_w, wqH, head_sw, 0, 32, 27, 864);
    packb_kernel<<<(110592 + 255) / 256, 256, 0, stream>>>(bb_w, BpB, bb_sw, 1, 32, 110592);
    packb_kernel<<<(9216 + 255) / 256, 256, 0, stream>>>(tr_w, BpT, tr_sw, 0, 12, 9216);

    // head
    head_kernel<<<dim3(8, 32, 8), 256, 0, stream>>>(x, wqH, head_b, head_sw, act_s, buf0);

    // backbone: 12 MFMA layers, ping-pong buf1/buf2 (buf0 preserved for residual)
    dim3 gridB(8, 16, 8);
    const unsigned char* cur = buf0;
    unsigned char* nxt = buf1;
    for (int l = 0; l < 12; ++l) {
        qconv_mfma_kernel<false><<<gridB, 256, 0, stream>>>(
            cur, nullptr, BpB + l * 9216, bb_b + l * 32, bb_sw, l, act_s, (void*)nxt);
        cur = nxt;
        nxt = (nxt == buf1) ? buf2 : buf1;
    }

    // tail: input = sat(cur + buf0), conv 32->12(pad 32), pixel-shuffle fp32 out
    qconv_mfma_kernel<true><<<gridB, 256, 0, stream>>>(
        cur, buf0, BpT, tr_b, tr_sw, 0, act_s, d_out);
}

// Round 6
// 349.450 us; speedup vs baseline: 5.9420x; 1.0834x over previous
//
#include <hip/hip_runtime.h>

typedef __bf16 bf16x8 __attribute__((ext_vector_type(8)));
typedef float  f32x16 __attribute__((ext_vector_type(16)));

// ---------------- head weight quant (scalar path, [k=ic*9+tap][oc] fp32) ----------------
__global__ __launch_bounds__(256) void quantw_kernel(
    const float* __restrict__ src, float* __restrict__ dst,
    const float* __restrict__ sw, int per_layer_sw, int OC, int ICK, int total)
{
    int i = blockIdx.x * 256 + threadIdx.x;
    if (i >= total) return;
    int per = OC * ICK;
    int l = i / per;
    int rem = i - l * per;
    int oc = rem / ICK;
    int k = rem - oc * ICK;
    float s = sw[per_layer_sw ? l : 0];
    float v = rintf(src[i] / s);
    v = fminf(fmaxf(v, -127.0f), 127.0f);
    dst[l * per + k * OC + oc] = v;
}

// ---------------- MFMA W prepack: dst[l][s][lane][j] bf16 bits ----------------
// k = s*16 + 8*(lane>>5) + j ; tap = k/32 ; ic = k%32 ; oc = lane&31
__global__ __launch_bounds__(256) void packb_kernel(
    const float* __restrict__ src, unsigned short* __restrict__ dst,
    const float* __restrict__ sw, int per_layer_sw, int OC_real, int total)
{
    int i = blockIdx.x * 256 + threadIdx.x;
    if (i >= total) return;
    int l   = i / 9216;
    int r   = i - l * 9216;
    int s   = r >> 9;
    int lane = (r >> 3) & 63;
    int j   = r & 7;
    int k   = s * 16 + ((lane >> 5) << 3) + j;
    int tap = k >> 5;
    int ic  = k & 31;
    int oc  = lane & 31;
    unsigned short v = 0;
    if (oc < OC_real) {
        float scale = sw[per_layer_sw ? l : 0];
        float w = src[((l * OC_real + oc) * 32 + ic) * 9 + tap];
        float q = rintf(w / scale);
        q = fminf(fmaxf(q, -127.0f), 127.0f);
        union { float f; unsigned int u; } cv; cv.f = q;
        v = (unsigned short)(cv.u >> 16);   // integers |q|<=127 exact in bf16
    }
    dst[i] = v;
}

// ---------------- head: fp32 x (NCHW) -> quant -> 3x3 conv -> u8 codes channel-last ----------------
__global__ __launch_bounds__(256) void head_kernel(
    const float* __restrict__ x, const float* __restrict__ wq,
    const float* __restrict__ bias, const float* __restrict__ sw_ptr,
    const float* __restrict__ s_ptr, unsigned char* __restrict__ out)
{
    __shared__ unsigned char tile[3][10][34];
    const int tid = threadIdx.x;
    const int x0 = blockIdx.x * 32;
    const int y0 = blockIdx.y * 8;
    const int b  = blockIdx.z;
    const float s = s_ptr[0];

    for (int ch = 0; ch < 3; ++ch) {
        const int base = (b * 3 + ch) << 16;
        for (int p = tid; p < 10 * 34; p += 256) {
            int r = p / 34, c = p - r * 34;
            int gy = y0 + r - 1, gx = x0 + c - 1;
            unsigned char v = 0;
            if ((unsigned)gy < 256u && (unsigned)gx < 256u) {
                float xv = x[base + (gy << 8) + gx];
                float q = (s == 1.0f) ? xv : (xv / s);
                q = rintf(q);
                q = fminf(fmaxf(q, 0.0f), 255.0f);
                v = (unsigned char)q;
            }
            tile[ch][r][c] = v;
        }
    }
    __syncthreads();

    const int c = tid & 31, r = tid >> 5;
    float acc[32];
    #pragma unroll
    for (int i = 0; i < 32; ++i) acc[i] = 0.0f;

    #pragma unroll
    for (int ic = 0; ic < 3; ++ic) {
        float a[9];
        #pragma unroll
        for (int dy = 0; dy < 3; ++dy)
            #pragma unroll
            for (int dx = 0; dx < 3; ++dx)
                a[dy * 3 + dx] = (float)tile[ic][r + dy][c + dx];
        #pragma unroll
        for (int t = 0; t < 9; ++t) {
            const float* wrow = wq + (ic * 9 + t) * 32;
            #pragma unroll
            for (int oc = 0; oc < 32; ++oc)
                acc[oc] = fmaf(a[t], wrow[oc], acc[oc]);
        }
    }

    const float alpha = s * sw_ptr[0];
    unsigned int w8[8] = {0,0,0,0,0,0,0,0};
    #pragma unroll
    for (int oc = 0; oc < 32; ++oc) {
        float y = fmaf(alpha, acc[oc], bias[oc]);
        y = fmaxf(y, 0.0f);
        float v = (s == 1.0f) ? y : (y / s);
        v = rintf(v);
        v = fminf(fmaxf(v, 0.0f), 255.0f);
        w8[oc >> 2] |= ((unsigned int)(unsigned char)v) << (8 * (oc & 3));
    }
    uint4* dst = (uint4*)(out + (size_t)((((b << 8) + (y0 + r)) << 8) + (x0 + c)) * 32);
    dst[0] = make_uint4(w8[0], w8[1], w8[2], w8[3]);
    dst[1] = make_uint4(w8[4], w8[5], w8[6], w8[7]);
}

// ---------------- backbone/tail: implicit-GEMM 3x3 conv via mfma_f32_32x32x16_bf16 ----------------
// D = W * Act^T : A-operand = weight frag (row=oc) read DIRECTLY FROM GLOBAL (L2-hot 18KB),
// B-operand = activation frag from LDS. LDS = A-tile only (39KB) -> 4 blocks/CU, grid fully
// resident in one round. dx-outer tap loop keeps only af[6] live (VGPR <= 128 for 16 waves/CU).
template<bool FINAL>
__global__ __launch_bounds__(256, 4) void qconv_mfma_kernel(
    const unsigned char* __restrict__ in,
    const unsigned char* __restrict__ resid,
    const unsigned short* __restrict__ Bp,   // [18][64][8] bf16 bits, fragment-ready
    const float* __restrict__ bias,
    const float* __restrict__ sw_ptr, int sw_idx,
    const float* __restrict__ s_ptr,
    void* __restrict__ out)
{
    __shared__ uint4 aT[2448];   // [yt:18][xt:34][cb:4] 16B chunks, cb XOR-swizzled by xt
    const int tid = threadIdx.x;
    const int x0 = blockIdx.x << 5;   // tile 32 wide
    const int y0 = blockIdx.y << 4;   // tile 16 high
    const int b  = blockIdx.z;

    // stage A tile: u8 -> bf16, swizzled chunks
    #pragma unroll
    for (int it = 0; it < 5; ++it) {
        int ci = tid + it * 256;
        if (ci < 1224) {                       // 18*34*2 half-pixel chunks
            int yt  = ci / 68;
            int rem = ci - yt * 68;
            int xt  = rem >> 1;
            int ch  = rem & 1;                 // which 16-channel half
            int gy = y0 + yt - 1;
            int gx = x0 + xt - 1;
            uint4 raw = make_uint4(0, 0, 0, 0);
            uint4 res = make_uint4(0, 0, 0, 0);
            if ((unsigned)gy < 256u && (unsigned)gx < 256u) {
                size_t off = (size_t)((((b << 8) + gy) << 8) + gx) * 32 + (ch << 4);
                raw = *(const uint4*)(in + off);
                if (FINAL) res = *(const uint4*)(resid + off);
            }
            unsigned int ow[8];
            const unsigned int* rw = (const unsigned int*)&raw;
            const unsigned int* rr = (const unsigned int*)&res;
            #pragma unroll
            for (int w = 0; w < 4; ++w) {
                unsigned int v = rw[w], rv = rr[w];
                #pragma unroll
                for (int hb = 0; hb < 2; ++hb) {
                    unsigned int a0 = (v >> (16 * hb)) & 0xffu;
                    unsigned int a1 = (v >> (16 * hb + 8)) & 0xffu;
                    if (FINAL) {
                        a0 += (rv >> (16 * hb)) & 0xffu;      if (a0 > 255u) a0 = 255u;
                        a1 += (rv >> (16 * hb + 8)) & 0xffu;  if (a1 > 255u) a1 = 255u;
                    }
                    union { float f; unsigned int u; } c0, c1;
                    c0.f = (float)a0; c1.f = (float)a1;       // integers <=255: exact in bf16
                    ow[2 * w + hb] = (c0.u >> 16) | (c1.u & 0xffff0000u);
                }
            }
            int swz  = (xt & 3) ^ ((xt >> 2) & 3);
            int base = (yt * 34 + xt) << 2;
            aT[base + (((ch << 1) + 0) ^ swz)] = make_uint4(ow[0], ow[1], ow[2], ow[3]);
            aT[base + (((ch << 1) + 1) ^ swz)] = make_uint4(ow[4], ow[5], ow[6], ow[7]);
        }
    }
    __syncthreads();

    const int lane = tid & 63;
    const int wid  = tid >> 6;
    const int px   = lane & 31;
    const int half = lane >> 5;
    const int py0  = wid << 2;      // 4 pixel-rows per wave

    const bf16x8* Wg = (const bf16x8*)Bp;   // weight frags straight from global (L2-hot)

    f32x16 acc[4];
    #pragma unroll
    for (int p = 0; p < 4; ++p)
        #pragma unroll
        for (int i = 0; i < 16; ++i) acc[p][i] = 0.0f;

    #pragma unroll
    for (int ich = 0; ich < 2; ++ich) {
        const int cb = (ich << 1) + half;
        #pragma unroll
        for (int dx = 0; dx < 3; ++dx) {
            // act frags for this (ich,dx): rows py0..py0+5 — only 6 frags live
            const int xt = px + dx;
            const int cbs = cb ^ ((xt & 3) ^ ((xt >> 2) & 3));
            bf16x8 af[6];
            #pragma unroll
            for (int yl = 0; yl < 6; ++yl)
                af[yl] = *(const bf16x8*)&aT[((py0 + yl) * 34 + xt) * 4 + cbs];
            #pragma unroll
            for (int dy = 0; dy < 3; ++dy) {
                bf16x8 wfr = Wg[(((dy * 3 + dx) << 1) + ich) * 64 + lane];
                acc[0] = __builtin_amdgcn_mfma_f32_32x32x16_bf16(wfr, af[dy + 0], acc[0], 0, 0, 0);
                acc[1] = __builtin_amdgcn_mfma_f32_32x32x16_bf16(wfr, af[dy + 1], acc[1], 0, 0, 0);
                acc[2] = __builtin_amdgcn_mfma_f32_32x32x16_bf16(wfr, af[dy + 2], acc[2], 0, 0, 0);
                acc[3] = __builtin_amdgcn_mfma_f32_32x32x16_bf16(wfr, af[dy + 3], acc[3], 0, 0, 0);
            }
        }
    }

    // epilogue: D col = lane&31 = pixel-x ; row r -> oc = (r&3) + 8*(r>>2) + 4*half
    const float s = s_ptr[0];
    const float alpha = s * sw_ptr[sw_idx];
    const int gx = x0 + px;

    if (!FINAL) {
        float bv[16];
        #pragma unroll
        for (int r = 0; r < 16; ++r)
            bv[r] = bias[(r & 3) + ((r >> 2) << 3) + (half << 2)];
        #pragma unroll
        for (int py = 0; py < 4; ++py) {
            const int gy = y0 + py0 + py;
            unsigned char* pout = (unsigned char*)out + (((size_t)((((b << 8) + gy) << 8) + gx)) << 5);
            #pragma unroll
            for (int q = 0; q < 4; ++q) {
                unsigned int wv = 0;
                #pragma unroll
                for (int j = 0; j < 4; ++j) {
                    float y = fmaf(alpha, acc[py][4 * q + j], bv[4 * q + j]);
                    y = fmaxf(y, 0.0f);
                    float v = (s == 1.0f) ? y : (y / s);
                    v = rintf(v);
                    v = fminf(fmaxf(v, 0.0f), 255.0f);
                    wv |= ((unsigned int)v) << (8 * j);
                }
                *(unsigned int*)(pout + 8 * q + 4 * half) = wv;
            }
        }
    } else {
        #pragma unroll
        for (int py = 0; py < 4; ++py) {
            const int gy = y0 + py0 + py;
            #pragma unroll
            for (int r = 0; r < 16; ++r) {
                const int oc = (r & 3) + ((r >> 2) << 3) + (half << 2);
                if (oc < 12) {
                    float y = fmaf(alpha, acc[py][r], bias[oc]);
                    y = fmaxf(y, 0.0f);
                    float v = (s == 1.0f) ? y : (y / s);
                    v = rintf(v);
                    v = fminf(fmaxf(v, 0.0f), 255.0f);
                    float o = (s == 1.0f) ? v : fminf(fmaxf(s * v, 0.0f), 255.0f);
                    const int cc = oc >> 2, r1 = (oc >> 1) & 1, r2 = oc & 1;
                    ((float*)out)[(size_t)(((b * 3 + cc) << 9) + (gy << 1) + r1) * 512 + (gx << 1) + r2] = o;
                }
            }
        }
    }
}

extern "C" void kernel_launch(void* const* d_in, const int* in_sizes, int n_in,
                              void* d_out, int out_size, void* d_ws, size_t ws_size,
                              hipStream_t stream) {
    const float* x       = (const float*)d_in[0];
    const float* head_w  = (const float*)d_in[1];
    const float* head_b  = (const float*)d_in[2];
    const float* head_sw = (const float*)d_in[3];
    const float* bb_w    = (const float*)d_in[4];
    const float* bb_b    = (const float*)d_in[5];
    const float* bb_sw   = (const float*)d_in[6];
    const float* tr_w    = (const float*)d_in[7];
    const float* tr_b    = (const float*)d_in[8];
    const float* tr_sw   = (const float*)d_in[9];
    const float* act_s   = (const float*)d_in[10];

    char* ws = (char*)d_ws;
    unsigned char* buf0 = (unsigned char*)ws;            // y0, channel-last u8 [8][256][256][32]
    unsigned char* buf1 = buf0 + 16777216;
    unsigned char* buf2 = buf1 + 16777216;
    float* wqH = (float*)(ws + 50331648);                         // [27][32] fp32
    unsigned short* BpB = (unsigned short*)(ws + 50331648 + 4096); // 12 x [18][64][8] bf16
    unsigned short* BpT = BpB + 110592;                            // [18][64][8] bf16

    quantw_kernel<<<(864 + 255) / 256, 256, 0, stream>>>(head_w, wqH, head_sw, 0, 32, 27, 864);
    packb_kernel<<<(110592 + 255) / 256, 256, 0, stream>>>(bb_w, BpB, bb_sw, 1, 32, 110592);
    packb_kernel<<<(9216 + 255) / 256, 256, 0, stream>>>(tr_w, BpT, tr_sw, 0, 12, 9216);

    // head
    head_kernel<<<dim3(8, 32, 8), 256, 0, stream>>>(x, wqH, head_b, head_sw, act_s, buf0);

    // backbone: 12 MFMA layers, ping-pong buf1/buf2 (buf0 preserved for residual)
    dim3 gridB(8, 16, 8);
    const unsigned char* cur = buf0;
    unsigned char* nxt = buf1;
    for (int l = 0; l < 12; ++l) {
        qconv_mfma_kernel<false><<<gridB, 256, 0, stream>>>(
            cur, nullptr, BpB + l * 9216, bb_b + l * 32, bb_sw, l, act_s, (void*)nxt);
        cur = nxt;
        nxt = (nxt == buf1) ? buf2 : buf1;
    }

    // tail: input = sat(cur + buf0), conv 32->12(pad 32), pixel-shuffle fp32 out
    qconv_mfma_kernel<true><<<gridB, 256, 0, stream>>>(
        cur, buf0, BpT, tr_b, tr_sw, 0, act_s, d_out);
}